// Round 20
// baseline (91.010 us; speedup 1.0000x reference)
//
#include <hip/hip_runtime.h>
#include <stdint.h>

#define SL 4096
#define DM 1024
#define NH 16
#define HDIM 64

typedef short short8 __attribute__((ext_vector_type(8)));
typedef float f32x4 __attribute__((ext_vector_type(4)));

__device__ __forceinline__ unsigned short f2bf(float f) {
  unsigned int u = __float_as_uint(f);
  u += 0x7FFF + ((u >> 16) & 1);
  return (unsigned short)(u >> 16);
}
__device__ __forceinline__ float bf2f(unsigned short u) {
  return __uint_as_float((unsigned int)u << 16);
}
__device__ __forceinline__ float bflo(unsigned int u) { return __uint_as_float(u << 16); }
__device__ __forceinline__ float bfhi(unsigned int u) { return __uint_as_float(u & 0xffff0000u); }

__device__ __forceinline__ void gload_lds16(const void* g, void* l) {
  __builtin_amdgcn_global_load_lds((const __attribute__((address_space(1))) void*)g,
                                   (__attribute__((address_space(3))) void*)l, 16, 0, 0);
}
#define SBAR()                                  \
  do {                                          \
    __builtin_amdgcn_sched_barrier(0);          \
    __builtin_amdgcn_s_barrier();               \
    __builtin_amdgcn_sched_barrier(0);          \
  } while (0)
#define LGKM0() asm volatile("s_waitcnt lgkmcnt(0)" ::: "memory")

// ---------------- fused cast: x + 4 weight mats ----------------
__global__ void cast_all(const float* __restrict__ x,
                         const float* __restrict__ Wq, const float* __restrict__ Wk,
                         const float* __restrict__ Wv, const float* __restrict__ Wo,
                         unsigned short* __restrict__ xb,
                         unsigned short* __restrict__ w3b, unsigned short* __restrict__ wob) {
  int i = blockIdx.x * blockDim.x + threadIdx.x;  // 0 .. 2*2^20-1
  const float* src;
  unsigned short* dst;
  int off;
  if (i < (1 << 20)) {
    src = x; dst = xb; off = i;
  } else {
    int wsel = i - (1 << 20);
    int seg = wsel >> 18;                         // 0..3
    off = wsel & 262143;
    src = (seg == 0) ? Wq : (seg == 1) ? Wk : (seg == 2) ? Wv : Wo;
    dst = (seg < 3) ? (w3b + (size_t)seg * DM * DM) : wob;
  }
  float4 v = ((const float4*)src)[off];
  ushort4 o = make_ushort4(f2bf(v.x), f2bf(v.y), f2bf(v.z), f2bf(v.w));
  ((ushort4*)dst)[off] = o;
}

// ============ GEMM1: 128x192 tile, BK=128 (two 64-wide halves), 8 waves =====
// gemm2_bk128-proven discipline scaled up: NT=8, 4-phase depth-2. ALL ds_reads
// in ph1 (half0) + ph2 (half1, LGKM0); t+2 staging ph3 (A, 4 loads) + ph4
// (B, 6 loads); ph4 vmcnt(10) = full-iteration-old loads. LDS 160 KB,
// 1 block/CU, grid 16x32 = 512 blocks. RoPE epilogue identical to r16.
__global__ __launch_bounds__(512, 2)
void gemm1_rope(const unsigned short* __restrict__ A,
                const unsigned short* __restrict__ B,
                unsigned short* __restrict__ C,
                const float* __restrict__ fc, const float* __restrict__ fs) {
  constexpr int K = 1024, LDA = 1024, LDC = 3072, NT = K / 128;  // 8
  __shared__ __align__(16) unsigned short As[2][2][128 * 64];    // 64 KB
  __shared__ __align__(16) unsigned short Bs[2][2][192 * 64];    // 96 KB
  const int tid = threadIdx.x, w = tid >> 6, lane = tid & 63;
  const int wr = w >> 2, wc = w & 3;  // 2 x 4 wave grid, wave-tile 64x48

  const int gx = gridDim.x;           // 16 (N tiles of 192)
  const int total = gx * gridDim.y;   // 512
  const int lin = blockIdx.y * gx + blockIdx.x;
  const int swz = (lin & 7) * (total >> 3) + (lin >> 3);
  const int brow = (swz / gx) * 128;
  const int bcol = (swz % gx) * 192;

  const unsigned short* gA[2];
  const unsigned short* gB[3];
#pragma unroll
  for (int l = 0; l < 2; ++l) {
    int idx = l * 512 + tid;            // 1024 chunks = 128 rows x 8
    int row_l = idx >> 3, c = idx & 7;
    int csrc = c ^ ((row_l >> 1) & 7);
    gA[l] = A + (size_t)(brow + row_l) * LDA + csrc * 8;
  }
#pragma unroll
  for (int l = 0; l < 3; ++l) {
    int idx = l * 512 + tid;            // 1536 chunks = 192 rows x 8
    int row_l = idx >> 3, c = idx & 7;
    int csrc = c ^ ((row_l >> 1) & 7);
    gB[l] = B + (size_t)(bcol + row_l) * LDA + csrc * 8;
  }

  auto STG_A = [&](int t, int h) {      // 2 loads: half h of A-tile t
    const int buf = t & 1;
#pragma unroll
    for (int l = 0; l < 2; ++l)
      gload_lds16(gA[l] + t * 128 + h * 64, &As[buf][h][(l * 512 + w * 64) * 8]);
  };
  auto STG_B = [&](int t, int h) {      // 3 loads: half h of B-tile t
    const int buf = t & 1;
#pragma unroll
    for (int l = 0; l < 3; ++l)
      gload_lds16(gB[l] + t * 128 + h * 64, &Bs[buf][h][(l * 512 + w * 64) * 8]);
  };

  const int lrow = lane & 15, h4 = lane >> 4;
  const int g3 = (lane >> 1) & 7;
  const int u2 = h4 ^ (g3 & 3);
  const int gv = g3 >> 2;
  const int co0 = ((((0 ^ gv) << 2) | u2)) * 8;
  const int co1 = ((((1 ^ gv) << 2) | u2)) * 8;

  f32x4 acc[4][3] = {};
  short8 a0[4], a1[4], a2[4], a3[4], b0[3], b1[3], b2[3], b3[3];

  // prologue: tiles 0 and 1 fully staged (10 loads each); wait tile 0
  STG_A(0, 0); STG_A(0, 1); STG_B(0, 0); STG_B(0, 1);
  STG_A(1, 0); STG_A(1, 1); STG_B(1, 0); STG_B(1, 1);
  asm volatile("s_waitcnt vmcnt(10)" ::: "memory");
  SBAR();

  for (int t = 0; t < NT; ++t) {
    const int buf = t & 1;
    const unsigned short* Ab0 = &As[buf][0][(wr * 64 + lrow) * 64];
    const unsigned short* Ab1 = &As[buf][1][(wr * 64 + lrow) * 64];
    const unsigned short* Bb0 = &Bs[buf][0][(wc * 48 + lrow) * 64];
    const unsigned short* Bb1 = &Bs[buf][1][(wc * 48 + lrow) * 64];
    // ---- phase 1: read ALL half0 frags (14); MFMA slice0
#pragma unroll
    for (int n = 0; n < 3; ++n) { b0[n] = *(const short8*)&Bb0[n * 16 * 64 + co0];
                                  b1[n] = *(const short8*)&Bb0[n * 16 * 64 + co1]; }
#pragma unroll
    for (int m = 0; m < 4; ++m) { a0[m] = *(const short8*)&Ab0[m * 16 * 64 + co0];
                                  a1[m] = *(const short8*)&Ab0[m * 16 * 64 + co1]; }
    SBAR();
    __builtin_amdgcn_s_setprio(1);
#pragma unroll
    for (int m = 0; m < 4; ++m)
#pragma unroll
      for (int n = 0; n < 3; ++n)
        acc[m][n] = __builtin_amdgcn_mfma_f32_16x16x32_bf16(a0[m], b0[n], acc[m][n], 0, 0, 0);
    __builtin_amdgcn_s_setprio(0);
    // ---- phase 2: read ALL half1 frags (14); LGKM0; MFMA slice1
#pragma unroll
    for (int n = 0; n < 3; ++n) { b2[n] = *(const short8*)&Bb1[n * 16 * 64 + co0];
                                  b3[n] = *(const short8*)&Bb1[n * 16 * 64 + co1]; }
#pragma unroll
    for (int m = 0; m < 4; ++m) { a2[m] = *(const short8*)&Ab1[m * 16 * 64 + co0];
                                  a3[m] = *(const short8*)&Ab1[m * 16 * 64 + co1]; }
    LGKM0();   // all reads of this buffer retired before ph3 staging
    SBAR();
    __builtin_amdgcn_s_setprio(1);
#pragma unroll
    for (int m = 0; m < 4; ++m)
#pragma unroll
      for (int n = 0; n < 3; ++n)
        acc[m][n] = __builtin_amdgcn_mfma_f32_16x16x32_bf16(a1[m], b1[n], acc[m][n], 0, 0, 0);
    __builtin_amdgcn_s_setprio(0);
    // ---- phase 3: stage A(t+2) both halves; MFMA slice2
    if (t + 2 < NT) { STG_A(t + 2, 0); STG_A(t + 2, 1); }
    SBAR();
    __builtin_amdgcn_s_setprio(1);
#pragma unroll
    for (int m = 0; m < 4; ++m)
#pragma unroll
      for (int n = 0; n < 3; ++n)
        acc[m][n] = __builtin_amdgcn_mfma_f32_16x16x32_bf16(a2[m], b2[n], acc[m][n], 0, 0, 0);
    __builtin_amdgcn_s_setprio(0);
    // ---- phase 4: stage B(t+2) both halves; counted vmcnt; MFMA slice3
    if (t + 2 < NT) { STG_B(t + 2, 0); STG_B(t + 2, 1); }
    if (t >= NT - 2) {
      asm volatile("s_waitcnt vmcnt(0)" ::: "memory");
    } else {
      asm volatile("s_waitcnt vmcnt(10)" ::: "memory");
    }
    SBAR();
    __builtin_amdgcn_s_setprio(1);
#pragma unroll
    for (int m = 0; m < 4; ++m)
#pragma unroll
      for (int n = 0; n < 3; ++n)
        acc[m][n] = __builtin_amdgcn_mfma_f32_16x16x32_bf16(a3[m], b3[n], acc[m][n], 0, 0, 0);
    __builtin_amdgcn_s_setprio(0);
  }

  // ---- epilogue: RoPE (abs cols<2048, per-frag) + bf16 store (r16-identical)
  const int er = (lane >> 4) * 4;
  const int ec = lane & 15;
#pragma unroll
  for (int n = 0; n < 3; ++n) {
    if (bcol + wc * 48 + n * 16 < 2048) {
      const int p = ((wc * 48 + n * 16 + ec) & 63) >> 1;
#pragma unroll
      for (int m = 0; m < 4; ++m) {
#pragma unroll
        for (int r = 0; r < 4; ++r) {
          const int row = brow + wr * 64 + m * 16 + er + r;
          float v = acc[m][n][r];
          float pv = __shfl_xor(v, 1);
          float cs = fc[row * 32 + p], sn = fs[row * 32 + p];
          acc[m][n][r] = (lane & 1) ? (pv * sn + v * cs) : (v * cs - pv * sn);
        }
      }
    }
  }
#pragma unroll
  for (int m = 0; m < 4; ++m)
#pragma unroll
    for (int n = 0; n < 3; ++n) {
      unsigned short* cp = C + (size_t)(brow + wr * 64 + m * 16 + er) * LDC +
                           (bcol + wc * 48 + n * 16 + ec);
#pragma unroll
      for (int r = 0; r < 4; ++r) cp[(size_t)r * LDC] = f2bf(acc[m][n][r]);
    }
}

// ============ GEMM2: 128x128 tile, BK=128 (two 64-wide halves), 8 waves =====
// (r18-proven, frozen)
__global__ __launch_bounds__(512)
void gemm2_bk128(const unsigned short* __restrict__ A,
                 const unsigned short* __restrict__ B,
                 float* __restrict__ C) {
  constexpr int K = 1024, LDA = 1024, LDC = 1024, NT = K / 128;  // 8
  __shared__ __align__(16) unsigned short As2[2][2][128 * 64];   // [buf][half]
  __shared__ __align__(16) unsigned short Bs2[2][2][128 * 64];
  const int tid = threadIdx.x, w = tid >> 6, lane = tid & 63;
  const int wr = w >> 2, wc = w & 3;   // 2 x 4 wave grid, wave-tile 64x32

  const int gx = gridDim.x;            // 8
  const int total = gx * gridDim.y;    // 256
  const int lin = blockIdx.y * gx + blockIdx.x;
  const int swz = (lin & 7) * (total >> 3) + (lin >> 3);
  const int brow = (swz / gx) * 128;
  const int bcol = (swz % gx) * 128;

  const unsigned short* gA[2];
  const unsigned short* gB[2];
#pragma unroll
  for (int l = 0; l < 2; ++l) {
    int idx = l * 512 + tid;
    int row_l = idx >> 3, c = idx & 7;
    int csrc = c ^ ((row_l >> 1) & 7);
    gA[l] = A + (size_t)(brow + row_l) * LDA + csrc * 8;
    gB[l] = B + (size_t)(bcol + row_l) * LDA + csrc * 8;
  }

  auto STG_A = [&](int t, int h) {
    const int buf = t & 1;
#pragma unroll
    for (int l = 0; l < 2; ++l)
      gload_lds16(gA[l] + t * 128 + h * 64, &As2[buf][h][(l * 512 + w * 64) * 8]);
  };
  auto STG_B = [&](int t, int h) {
    const int buf = t & 1;
#pragma unroll
    for (int l = 0; l < 2; ++l)
      gload_lds16(gB[l] + t * 128 + h * 64, &Bs2[buf][h][(l * 512 + w * 64) * 8]);
  };

  const int lrow = lane & 15, h4 = lane >> 4;
  const int g3 = (lane >> 1) & 7;
  const int u2 = h4 ^ (g3 & 3);
  const int gv = g3 >> 2;
  const int co0 = ((((0 ^ gv) << 2) | u2)) * 8;
  const int co1 = ((((1 ^ gv) << 2) | u2)) * 8;

  f32x4 acc[4][2] = {};
  short8 a0[4], a1[4], a2[4], a3[4], b0[2], b1[2], b2[2], b3[2];

  STG_A(0, 0); STG_A(0, 1); STG_B(0, 0); STG_B(0, 1);
  STG_A(1, 0); STG_A(1, 1); STG_B(1, 0); STG_B(1, 1);
  asm volatile("s_waitcnt vmcnt(8)" ::: "memory");
  SBAR();

  for (int t = 0; t < NT; ++t) {
    const int buf = t & 1;
    const unsigned short* Ab0 = &As2[buf][0][(wr * 64 + lrow) * 64];
    const unsigned short* Ab1 = &As2[buf][1][(wr * 64 + lrow) * 64];
    const unsigned short* Bb0 = &Bs2[buf][0][(wc * 32 + lrow) * 64];
    const unsigned short* Bb1 = &Bs2[buf][1][(wc * 32 + lrow) * 64];
    // ---- phase 1: read half0 frags (12); MFMA slice0
#pragma unroll
    for (int n = 0; n < 2; ++n) { b0[n] = *(const short8*)&Bb0[n * 16 * 64 + co0];
                                  b1[n] = *(const short8*)&Bb0[n * 16 * 64 + co1]; }
#pragma unroll
    for (int m = 0; m < 4; ++m) { a0[m] = *(const short8*)&Ab0[m * 16 * 64 + co0];
                                  a1[m] = *(const short8*)&Ab0[m * 16 * 64 + co1]; }
    SBAR();
    __builtin_amdgcn_s_setprio(1);
#pragma unroll
    for (int m = 0; m < 4; ++m)
#pragma unroll
      for (int n = 0; n < 2; ++n)
        acc[m][n] = __builtin_amdgcn_mfma_f32_16x16x32_bf16(a0[m], b0[n], acc[m][n], 0, 0, 0);
    __builtin_amdgcn_s_setprio(0);
    // ---- phase 2: read half1 frags (12); LGKM0; MFMA slice1
#pragma unroll
    for (int n = 0; n < 2; ++n) { b2[n] = *(const short8*)&Bb1[n * 16 * 64 + co0];
                                  b3[n] = *(const short8*)&Bb1[n * 16 * 64 + co1]; }
#pragma unroll
    for (int m = 0; m < 4; ++m) { a2[m] = *(const short8*)&Ab1[m * 16 * 64 + co0];
                                  a3[m] = *(const short8*)&Ab1[m * 16 * 64 + co1]; }
    LGKM0();   // all reads of this buffer retired before ph3 staging
    SBAR();
    __builtin_amdgcn_s_setprio(1);
#pragma unroll
    for (int m = 0; m < 4; ++m)
#pragma unroll
      for (int n = 0; n < 2; ++n)
        acc[m][n] = __builtin_amdgcn_mfma_f32_16x16x32_bf16(a1[m], b1[n], acc[m][n], 0, 0, 0);
    __builtin_amdgcn_s_setprio(0);
    // ---- phase 3: stage A(t+2,h0)+B(t+2,h0); MFMA slice2
    if (t + 2 < NT) { STG_A(t + 2, 0); STG_B(t + 2, 0); }
    SBAR();
    __builtin_amdgcn_s_setprio(1);
#pragma unroll
    for (int m = 0; m < 4; ++m)
#pragma unroll
      for (int n = 0; n < 2; ++n)
        acc[m][n] = __builtin_amdgcn_mfma_f32_16x16x32_bf16(a2[m], b2[n], acc[m][n], 0, 0, 0);
    __builtin_amdgcn_s_setprio(0);
    // ---- phase 4: stage A(t+2,h1)+B(t+2,h1); counted vmcnt; MFMA slice3
    if (t + 2 < NT) { STG_A(t + 2, 1); STG_B(t + 2, 1); }
    if (t >= NT - 2) {
      asm volatile("s_waitcnt vmcnt(0)" ::: "memory");
    } else {
      asm volatile("s_waitcnt vmcnt(8)" ::: "memory");
    }
    SBAR();
    __builtin_amdgcn_s_setprio(1);
#pragma unroll
    for (int m = 0; m < 4; ++m)
#pragma unroll
      for (int n = 0; n < 2; ++n)
        acc[m][n] = __builtin_amdgcn_mfma_f32_16x16x32_bf16(a3[m], b3[n], acc[m][n], 0, 0, 0);
    __builtin_amdgcn_s_setprio(0);
  }

  const int er = (lane >> 4) * 4;
  const int ec = lane & 15;
#pragma unroll
  for (int m = 0; m < 4; ++m)
#pragma unroll
    for (int n = 0; n < 2; ++n) {
      float* cp = C + (size_t)(brow + wr * 64 + m * 16 + er) * LDC +
                  (bcol + wc * 32 + n * 16 + ec);
#pragma unroll
      for (int r = 0; r < 4; ++r) cp[(size_t)r * LDC] = acc[m][n][r];
    }
}

// ---------------- fused attention: rows 1..L-1 + row-0 flash partials ------
__global__ __launch_bounds__(256)
void attn_fused(const unsigned short* __restrict__ qkv, unsigned short* __restrict__ atb,
                float* __restrict__ prt) {
  const int wid = threadIdx.x >> 6;
  const int lane = threadIdx.x & 63;
  if (blockIdx.x >= 1024) {
    const int u = (blockIdx.x - 1024) * 4 + wid;
    const int p = u & 127, h = u >> 7;
    const float q = bf2f(qkv[h * 64 + lane]);
    float m = -1e30f, s = 0.f, o = 0.f;
    const int j0 = p * 32;
    for (int jj = 0; jj < 32; ++jj) {
      const int j = j0 + jj;
      float kv = bf2f(qkv[(size_t)j * 3072 + 1024 + h * 64 + lane]);
      float pr = q * kv;
#pragma unroll
      for (int off = 32; off; off >>= 1) pr += __shfl_xor(pr, off);
      pr *= 0.125f;
      float mn = fmaxf(m, pr);
      float c = __expf(m - mn);
      float e = __expf(pr - mn);
      float v = bf2f(qkv[(size_t)j * 3072 + 2048 + h * 64 + lane]);
      s = s * c + e;
      o = o * c + e * v;
      m = mn;
    }
    float* dst = prt + ((size_t)h * 128 + p) * 72;
    if (lane == 0) { dst[0] = m; dst[1] = s; }
    dst[2 + lane] = o;
    return;
  }

  const int i = blockIdx.x * 4 + wid + 1;
  if (i >= SL) return;
  const unsigned short* rowQ = qkv + (size_t)i * 3072 + lane * 16;

  float q[16];
  {
    uint4 a = *(const uint4*)rowQ;
    uint4 b = *(const uint4*)(rowQ + 8);
    unsigned int uu[8] = {a.x, a.y, a.z, a.w, b.x, b.y, b.z, b.w};
#pragma unroll
    for (int c = 0; c < 8; ++c) { q[2 * c] = bflo(uu[c]); q[2 * c + 1] = bfhi(uu[c]); }
  }

  float sc[9];
#pragma unroll
  for (int t = 0; t < 9; ++t) {
    int j = (t == 0) ? 0 : (i - 8 + t);
    bool valid = (t == 0) || (j >= 1);
    int jc = valid ? j : 0;
    const unsigned short* pk = qkv + (size_t)jc * 3072 + 1024 + lane * 16;
    uint4 a = *(const uint4*)pk;
    uint4 b = *(const uint4*)(pk + 8);
    unsigned int uu[8] = {a.x, a.y, a.z, a.w, b.x, b.y, b.z, b.w};
    float pr = 0.f;
#pragma unroll
    for (int c = 0; c < 8; ++c) pr += bflo(uu[c]) * q[2 * c] + bfhi(uu[c]) * q[2 * c + 1];
    pr += __shfl_xor(pr, 1);
    pr += __shfl_xor(pr, 2);
    sc[t] = valid ? pr * 0.125f : -1e30f;
  }

  float mx = sc[0];
#pragma unroll
  for (int t = 1; t < 9; ++t) mx = fmaxf(mx, sc[t]);
  float s = 0.f;
#pragma unroll
  for (int t = 0; t < 9; ++t) { float e = __expf(sc[t] - mx); sc[t] = e; s += e; }
  const float inv = 1.0f / s;

  float o[16] = {};
#pragma unroll
  for (int t = 0; t < 9; ++t) {
    int j = (t == 0) ? 0 : (i - 8 + t);
    bool valid = (t == 0) || (j >= 1);
    int jc = valid ? j : 0;
    const unsigned short* pv = qkv + (size_t)jc * 3072 + 2048 + lane * 16;
    uint4 a = *(const uint4*)pv;
    uint4 b = *(const uint4*)(pv + 8);
    unsigned int uu[8] = {a.x, a.y, a.z, a.w, b.x, b.y, b.z, b.w};
#pragma unroll
    for (int c = 0; c < 8; ++c) {
      o[2 * c]     += sc[t] * bflo(uu[c]);
      o[2 * c + 1] += sc[t] * bfhi(uu[c]);
    }
  }

  unsigned int wv[8];
#pragma unroll
  for (int c = 0; c < 8; ++c)
    wv[c] = (unsigned int)f2bf(o[2 * c] * inv) | ((unsigned int)f2bf(o[2 * c + 1] * inv) << 16);
  unsigned short* po = atb + (size_t)i * 1024 + lane * 16;
  uint4 s0; s0.x = wv[0]; s0.y = wv[1]; s0.z = wv[2]; s0.w = wv[3];
  uint4 s1; s1.x = wv[4]; s1.y = wv[5]; s1.z = wv[6]; s1.w = wv[7];
  *(uint4*)po = s0;
  *(uint4*)(po + 8) = s1;
}

// ---------------- row-0 combine: 16 blocks, wave-parallel over partials ----
__global__ __launch_bounds__(64)
void attn_row0_combine(const float* __restrict__ prt, unsigned short* __restrict__ atb) {
  const int h = blockIdx.x;
  const int lane = threadIdx.x;
  const float* base = prt + (size_t)h * 128 * 72;
  __shared__ float cbuf[128];
  float m0 = base[lane * 72];
  float m1 = base[(lane + 64) * 72];
  float M = fmaxf(m0, m1);
#pragma unroll
  for (int off = 32; off; off >>= 1) M = fmaxf(M, __shfl_xor(M, off));
  float c0 = __expf(m0 - M), c1 = __expf(m1 - M);
  float ls = base[lane * 72 + 1] * c0 + base[(lane + 64) * 72 + 1] * c1;
#pragma unroll
  for (int off = 32; off; off >>= 1) ls += __shfl_xor(ls, off);
  cbuf[lane] = c0;
  cbuf[lane + 64] = c1;
  __syncthreads();
  float o = 0.f;
#pragma unroll 8
  for (int p = 0; p < 128; ++p) o += cbuf[p] * base[p * 72 + 2 + lane];
  atb[h * 64 + lane] = f2bf(o / ls);
}

extern "C" void kernel_launch(void* const* d_in, const int* in_sizes, int n_in,
                              void* d_out, int out_size, void* d_ws, size_t ws_size,
                              hipStream_t stream) {
  const float* x  = (const float*)d_in[0];
  const float* Wq = (const float*)d_in[1];
  const float* Wk = (const float*)d_in[2];
  const float* Wv = (const float*)d_in[3];
  const float* Wo = (const float*)d_in[4];
  const float* fc = (const float*)d_in[5];
  const float* fs = (const float*)d_in[6];
  float* out = (float*)d_out;

  char* ws = (char*)d_ws;
  unsigned short* xb   = (unsigned short*)(ws);                      // 8 MB  bf16 x
  unsigned short* w3b  = (unsigned short*)(ws + ((size_t)8 << 20));  // 6 MB  bf16 [Wq;Wk;Wv]
  unsigned short* wob  = (unsigned short*)(ws + ((size_t)14 << 20)); // 2 MB  bf16 Wo
  unsigned short* qkvb = (unsigned short*)(ws + ((size_t)16 << 20)); // 24 MB bf16 QKV (roped)
  unsigned short* atb  = (unsigned short*)(ws + ((size_t)40 << 20)); // 8 MB  bf16 attn out
  float*          prt  = (float*)(ws + ((size_t)48 << 20));          // 0.6 MB row0 partials

  cast_all<<<(2 * (1 << 20)) / 256, 256, 0, stream>>>(x, Wq, Wk, Wv, Wo, xb, w3b, wob);

  // GEMM1: 128x192 tile, BK=128 4-phase depth-2, grid 16x32 = 512 blocks
  dim3 g1(3072 / 192, SL / 128);
  gemm1_rope<<<g1, 512, 0, stream>>>(xb, w3b, qkvb, fc, fs);

  attn_fused<<<1536, 256, 0, stream>>>(qkvb, atb, prt);
  attn_row0_combine<<<NH, 64, 0, stream>>>(prt, atb);

  // GEMM2: 128x128 tile, BK=128 4-phase depth-2, 8 waves, grid 8x32 = 256
  dim3 g2(DM / 128, SL / 128);
  gemm2_bk128<<<g2, 512, 0, stream>>>(atb, wob, out);
}

// Round 21
// 87.436 us; speedup vs baseline: 1.0409x; 1.0409x over previous
//
#include <hip/hip_runtime.h>
#include <stdint.h>

#define SL 4096
#define DM 1024
#define NH 16
#define HDIM 64

typedef short short8 __attribute__((ext_vector_type(8)));
typedef float f32x4 __attribute__((ext_vector_type(4)));

__device__ __forceinline__ unsigned short f2bf(float f) {
  unsigned int u = __float_as_uint(f);
  u += 0x7FFF + ((u >> 16) & 1);
  return (unsigned short)(u >> 16);
}
__device__ __forceinline__ float bf2f(unsigned short u) {
  return __uint_as_float((unsigned int)u << 16);
}
__device__ __forceinline__ float bflo(unsigned int u) { return __uint_as_float(u << 16); }
__device__ __forceinline__ float bfhi(unsigned int u) { return __uint_as_float(u & 0xffff0000u); }

__device__ __forceinline__ void gload_lds16(const void* g, void* l) {
  __builtin_amdgcn_global_load_lds((const __attribute__((address_space(1))) void*)g,
                                   (__attribute__((address_space(3))) void*)l, 16, 0, 0);
}
#define SBAR()                                  \
  do {                                          \
    __builtin_amdgcn_sched_barrier(0);          \
    __builtin_amdgcn_s_barrier();               \
    __builtin_amdgcn_sched_barrier(0);          \
  } while (0)
#define LGKM0() asm volatile("s_waitcnt lgkmcnt(0)" ::: "memory")

// ---------------- fused cast: x + 4 weight mats ----------------
__global__ void cast_all(const float* __restrict__ x,
                         const float* __restrict__ Wq, const float* __restrict__ Wk,
                         const float* __restrict__ Wv, const float* __restrict__ Wo,
                         unsigned short* __restrict__ xb,
                         unsigned short* __restrict__ w3b, unsigned short* __restrict__ wob) {
  int i = blockIdx.x * blockDim.x + threadIdx.x;  // 0 .. 2*2^20-1
  const float* src;
  unsigned short* dst;
  int off;
  if (i < (1 << 20)) {
    src = x; dst = xb; off = i;
  } else {
    int wsel = i - (1 << 20);
    int seg = wsel >> 18;                         // 0..3
    off = wsel & 262143;
    src = (seg == 0) ? Wq : (seg == 1) ? Wk : (seg == 2) ? Wv : Wo;
    dst = (seg < 3) ? (w3b + (size_t)seg * DM * DM) : wob;
  }
  float4 v = ((const float4*)src)[off];
  ushort4 o = make_ushort4(f2bf(v.x), f2bf(v.y), f2bf(v.z), f2bf(v.w));
  ((ushort4*)dst)[off] = o;
}

// ============ GEMM1: 128x192 tile, BK=64, 8 waves, 4-phase, DEPTH-2 =========
// (r16-proven, 2 blocks/CU — best measured GEMM1 config.) Reads ph1-2 only,
// LGKM0 in ph2, same-buffer t+2 staging ph3-4, ph4 vmcnt(5).
__global__ __launch_bounds__(512, 4)
void gemm1_rope(const unsigned short* __restrict__ A,
                const unsigned short* __restrict__ B,
                unsigned short* __restrict__ C,
                const float* __restrict__ fc, const float* __restrict__ fs) {
  constexpr int K = 1024, LDA = 1024, LDC = 3072, NT = K / 64;
  __shared__ __align__(16) unsigned short As[2][128 * 64];
  __shared__ __align__(16) unsigned short Bs[2][192 * 64];
  const int tid = threadIdx.x, w = tid >> 6, lane = tid & 63;
  const int wr = w >> 2, wc = w & 3;  // 2 x 4 wave grid, wave-tile 64x48

  const int gx = gridDim.x;           // 16 (N tiles of 192)
  const int total = gx * gridDim.y;   // 512
  const int lin = blockIdx.y * gx + blockIdx.x;
  const int swz = (lin & 7) * (total >> 3) + (lin >> 3);
  const int brow = (swz / gx) * 128;
  const int bcol = (swz % gx) * 192;

  const unsigned short* gA[2];
  const unsigned short* gB[3];
#pragma unroll
  for (int l = 0; l < 2; ++l) {
    int idx = l * 512 + tid;            // rows [0,128)
    int row_l = idx >> 3, c = idx & 7;
    int csrc = c ^ ((row_l >> 1) & 7);
    gA[l] = A + (size_t)(brow + row_l) * LDA + csrc * 8;
  }
#pragma unroll
  for (int l = 0; l < 3; ++l) {
    int idx = l * 512 + tid;            // rows [0,192)
    int row_l = idx >> 3, c = idx & 7;
    int csrc = c ^ ((row_l >> 1) & 7);
    gB[l] = B + (size_t)(bcol + row_l) * LDA + csrc * 8;
  }

  auto STG_A = [&](int t) {             // 2 loads, rows [0,128)
    const int buf = t & 1;
#pragma unroll
    for (int l = 0; l < 2; ++l)
      gload_lds16(gA[l] + t * 64, &As[buf][(l * 512 + w * 64) * 8]);
  };
  auto STG_B_a = [&](int t) {           // 2 loads, rows [0,128)
    const int buf = t & 1;
#pragma unroll
    for (int l = 0; l < 2; ++l)
      gload_lds16(gB[l] + t * 64, &Bs[buf][(l * 512 + w * 64) * 8]);
  };
  auto STG_B_b = [&](int t) {           // 1 load, rows [128,192)
    const int buf = t & 1;
    gload_lds16(gB[2] + t * 64, &Bs[buf][(2 * 512 + w * 64) * 8]);
  };

  const int lrow = lane & 15, h4 = lane >> 4;
  const int g3 = (lane >> 1) & 7;
  const int u2 = h4 ^ (g3 & 3);
  const int gv = g3 >> 2;
  const int co0 = ((((0 ^ gv) << 2) | u2)) * 8;
  const int co1 = ((((1 ^ gv) << 2) | u2)) * 8;

  f32x4 acc[4][3] = {};
  short8 a0[4], a1[4], b0[3], b1[3];

  // prologue: tiles 0 and 1 fully staged (5 loads each); wait tile 0
  STG_A(0); STG_B_a(0); STG_B_b(0);
  STG_A(1); STG_B_a(1); STG_B_b(1);
  asm volatile("s_waitcnt vmcnt(5)" ::: "memory");
  SBAR();

  for (int t = 0; t < NT; ++t) {
    const int buf = t & 1;
    const unsigned short* Ab = &As[buf][(wr * 64 + lrow) * 64];
    const unsigned short* Bb = &Bs[buf][(wc * 48 + lrow) * 64];
    // ---- phase 1: read k0 frags; MFMA ks0 (all 12)
#pragma unroll
    for (int n = 0; n < 3; ++n) b0[n] = *(const short8*)&Bb[n * 16 * 64 + co0];
#pragma unroll
    for (int m = 0; m < 4; ++m) a0[m] = *(const short8*)&Ab[m * 16 * 64 + co0];
    SBAR();
    __builtin_amdgcn_s_setprio(1);
#pragma unroll
    for (int m = 0; m < 4; ++m)
#pragma unroll
      for (int n = 0; n < 3; ++n)
        acc[m][n] = __builtin_amdgcn_mfma_f32_16x16x32_bf16(a0[m], b0[n], acc[m][n], 0, 0, 0);
    __builtin_amdgcn_s_setprio(0);
    // ---- phase 2: read k1 frags; LGKM0; MFMA ks1 n0
#pragma unroll
    for (int n = 0; n < 3; ++n) b1[n] = *(const short8*)&Bb[n * 16 * 64 + co1];
#pragma unroll
    for (int m = 0; m < 4; ++m) a1[m] = *(const short8*)&Ab[m * 16 * 64 + co1];
    LGKM0();   // all reads of this buffer retired before ph3 staging
    SBAR();
    __builtin_amdgcn_s_setprio(1);
#pragma unroll
    for (int m = 0; m < 4; ++m)
      acc[m][0] = __builtin_amdgcn_mfma_f32_16x16x32_bf16(a1[m], b1[0], acc[m][0], 0, 0, 0);
    __builtin_amdgcn_s_setprio(0);
    // ---- phase 3: stage A(t+2); MFMA ks1 n1
    if (t + 2 < NT) STG_A(t + 2);
    SBAR();
    __builtin_amdgcn_s_setprio(1);
#pragma unroll
    for (int m = 0; m < 4; ++m)
      acc[m][1] = __builtin_amdgcn_mfma_f32_16x16x32_bf16(a1[m], b1[1], acc[m][1], 0, 0, 0);
    __builtin_amdgcn_s_setprio(0);
    // ---- phase 4: stage B(t+2); counted vmcnt; MFMA ks1 n2
    if (t + 2 < NT) { STG_B_a(t + 2); STG_B_b(t + 2); }
    if (t >= NT - 2) {
      asm volatile("s_waitcnt vmcnt(0)" ::: "memory");
    } else {
      asm volatile("s_waitcnt vmcnt(5)" ::: "memory");
    }
    SBAR();
    __builtin_amdgcn_s_setprio(1);
#pragma unroll
    for (int m = 0; m < 4; ++m)
      acc[m][2] = __builtin_amdgcn_mfma_f32_16x16x32_bf16(a1[m], b1[2], acc[m][2], 0, 0, 0);
    __builtin_amdgcn_s_setprio(0);
  }

  // ---- epilogue: RoPE (abs cols<2048, per-frag) + bf16 store
  const int er = (lane >> 4) * 4;
  const int ec = lane & 15;
#pragma unroll
  for (int n = 0; n < 3; ++n) {
    if (bcol + wc * 48 + n * 16 < 2048) {
      const int p = ((wc * 48 + n * 16 + ec) & 63) >> 1;
#pragma unroll
      for (int m = 0; m < 4; ++m) {
#pragma unroll
        for (int r = 0; r < 4; ++r) {
          const int row = brow + wr * 64 + m * 16 + er + r;
          float v = acc[m][n][r];
          float pv = __shfl_xor(v, 1);
          float cs = fc[row * 32 + p], sn = fs[row * 32 + p];
          acc[m][n][r] = (lane & 1) ? (pv * sn + v * cs) : (v * cs - pv * sn);
        }
      }
    }
  }
#pragma unroll
  for (int m = 0; m < 4; ++m)
#pragma unroll
    for (int n = 0; n < 3; ++n) {
      unsigned short* cp = C + (size_t)(brow + wr * 64 + m * 16 + er) * LDC +
                           (bcol + wc * 48 + n * 16 + ec);
#pragma unroll
      for (int r = 0; r < 4; ++r) cp[(size_t)r * LDC] = f2bf(acc[m][n][r]);
    }
}

// ============ GEMM2: 128x128 tile, BK=128 (two 64-wide halves), 8 waves =====
// (r18-proven) NO XCD swizzle: per-XCD round-robin then gives each XCD one
// A-panel (1 MB) + all of Wo (2 MB) = 3 MB < 4 MB L2 -> L2-resident.
__global__ __launch_bounds__(512)
void gemm2_bk128(const unsigned short* __restrict__ A,
                 const unsigned short* __restrict__ B,
                 float* __restrict__ C) {
  constexpr int K = 1024, LDA = 1024, LDC = 1024, NT = K / 128;  // 8
  __shared__ __align__(16) unsigned short As2[2][2][128 * 64];   // [buf][half]
  __shared__ __align__(16) unsigned short Bs2[2][2][128 * 64];
  const int tid = threadIdx.x, w = tid >> 6, lane = tid & 63;
  const int wr = w >> 2, wc = w & 3;   // 2 x 4 wave grid, wave-tile 64x32

  const int gx = gridDim.x;            // 8
  const int lin = blockIdx.y * gx + blockIdx.x;
  const int swz = lin;                 // no XCD swizzle (L2-set arithmetic)
  const int brow = (swz / gx) * 128;
  const int bcol = (swz % gx) * 128;

  const unsigned short* gA[2];
  const unsigned short* gB[2];
#pragma unroll
  for (int l = 0; l < 2; ++l) {
    int idx = l * 512 + tid;
    int row_l = idx >> 3, c = idx & 7;
    int csrc = c ^ ((row_l >> 1) & 7);
    gA[l] = A + (size_t)(brow + row_l) * LDA + csrc * 8;
    gB[l] = B + (size_t)(bcol + row_l) * LDA + csrc * 8;
  }

  auto STG_A = [&](int t, int h) {
    const int buf = t & 1;
#pragma unroll
    for (int l = 0; l < 2; ++l)
      gload_lds16(gA[l] + t * 128 + h * 64, &As2[buf][h][(l * 512 + w * 64) * 8]);
  };
  auto STG_B = [&](int t, int h) {
    const int buf = t & 1;
#pragma unroll
    for (int l = 0; l < 2; ++l)
      gload_lds16(gB[l] + t * 128 + h * 64, &Bs2[buf][h][(l * 512 + w * 64) * 8]);
  };

  const int lrow = lane & 15, h4 = lane >> 4;
  const int g3 = (lane >> 1) & 7;
  const int u2 = h4 ^ (g3 & 3);
  const int gv = g3 >> 2;
  const int co0 = ((((0 ^ gv) << 2) | u2)) * 8;
  const int co1 = ((((1 ^ gv) << 2) | u2)) * 8;

  f32x4 acc[4][2] = {};
  short8 a0[4], a1[4], a2[4], a3[4], b0[2], b1[2], b2[2], b3[2];

  STG_A(0, 0); STG_A(0, 1); STG_B(0, 0); STG_B(0, 1);
  STG_A(1, 0); STG_A(1, 1); STG_B(1, 0); STG_B(1, 1);
  asm volatile("s_waitcnt vmcnt(8)" ::: "memory");
  SBAR();

  for (int t = 0; t < NT; ++t) {
    const int buf = t & 1;
    const unsigned short* Ab0 = &As2[buf][0][(wr * 64 + lrow) * 64];
    const unsigned short* Ab1 = &As2[buf][1][(wr * 64 + lrow) * 64];
    const unsigned short* Bb0 = &Bs2[buf][0][(wc * 32 + lrow) * 64];
    const unsigned short* Bb1 = &Bs2[buf][1][(wc * 32 + lrow) * 64];
    // ---- phase 1: read half0 frags (12); MFMA slice0
#pragma unroll
    for (int n = 0; n < 2; ++n) { b0[n] = *(const short8*)&Bb0[n * 16 * 64 + co0];
                                  b1[n] = *(const short8*)&Bb0[n * 16 * 64 + co1]; }
#pragma unroll
    for (int m = 0; m < 4; ++m) { a0[m] = *(const short8*)&Ab0[m * 16 * 64 + co0];
                                  a1[m] = *(const short8*)&Ab0[m * 16 * 64 + co1]; }
    SBAR();
    __builtin_amdgcn_s_setprio(1);
#pragma unroll
    for (int m = 0; m < 4; ++m)
#pragma unroll
      for (int n = 0; n < 2; ++n)
        acc[m][n] = __builtin_amdgcn_mfma_f32_16x16x32_bf16(a0[m], b0[n], acc[m][n], 0, 0, 0);
    __builtin_amdgcn_s_setprio(0);
    // ---- phase 2: read half1 frags (12); LGKM0; MFMA slice1
#pragma unroll
    for (int n = 0; n < 2; ++n) { b2[n] = *(const short8*)&Bb1[n * 16 * 64 + co0];
                                  b3[n] = *(const short8*)&Bb1[n * 16 * 64 + co1]; }
#pragma unroll
    for (int m = 0; m < 4; ++m) { a2[m] = *(const short8*)&Ab1[m * 16 * 64 + co0];
                                  a3[m] = *(const short8*)&Ab1[m * 16 * 64 + co1]; }
    LGKM0();   // all reads of this buffer retired before ph3 staging
    SBAR();
    __builtin_amdgcn_s_setprio(1);
#pragma unroll
    for (int m = 0; m < 4; ++m)
#pragma unroll
      for (int n = 0; n < 2; ++n)
        acc[m][n] = __builtin_amdgcn_mfma_f32_16x16x32_bf16(a1[m], b1[n], acc[m][n], 0, 0, 0);
    __builtin_amdgcn_s_setprio(0);
    // ---- phase 3: stage A(t+2,h0)+B(t+2,h0); MFMA slice2
    if (t + 2 < NT) { STG_A(t + 2, 0); STG_B(t + 2, 0); }
    SBAR();
    __builtin_amdgcn_s_setprio(1);
#pragma unroll
    for (int m = 0; m < 4; ++m)
#pragma unroll
      for (int n = 0; n < 2; ++n)
        acc[m][n] = __builtin_amdgcn_mfma_f32_16x16x32_bf16(a2[m], b2[n], acc[m][n], 0, 0, 0);
    __builtin_amdgcn_s_setprio(0);
    // ---- phase 4: stage A(t+2,h1)+B(t+2,h1); counted vmcnt; MFMA slice3
    if (t + 2 < NT) { STG_A(t + 2, 1); STG_B(t + 2, 1); }
    if (t >= NT - 2) {
      asm volatile("s_waitcnt vmcnt(0)" ::: "memory");
    } else {
      asm volatile("s_waitcnt vmcnt(8)" ::: "memory");
    }
    SBAR();
    __builtin_amdgcn_s_setprio(1);
#pragma unroll
    for (int m = 0; m < 4; ++m)
#pragma unroll
      for (int n = 0; n < 2; ++n)
        acc[m][n] = __builtin_amdgcn_mfma_f32_16x16x32_bf16(a3[m], b3[n], acc[m][n], 0, 0, 0);
    __builtin_amdgcn_s_setprio(0);
  }

  const int er = (lane >> 4) * 4;
  const int ec = lane & 15;
#pragma unroll
  for (int m = 0; m < 4; ++m)
#pragma unroll
    for (int n = 0; n < 2; ++n) {
      float* cp = C + (size_t)(brow + wr * 64 + m * 16 + er) * LDC +
                  (bcol + wc * 32 + n * 16 + ec);
#pragma unroll
      for (int r = 0; r < 4; ++r) cp[(size_t)r * LDC] = acc[m][n][r];
    }
}

// ---------------- fused attention: rows 1..L-1 + row-0 flash partials ------
__global__ __launch_bounds__(256)
void attn_fused(const unsigned short* __restrict__ qkv, unsigned short* __restrict__ atb,
                float* __restrict__ prt) {
  const int wid = threadIdx.x >> 6;
  const int lane = threadIdx.x & 63;
  if (blockIdx.x >= 1024) {
    const int u = (blockIdx.x - 1024) * 4 + wid;
    const int p = u & 127, h = u >> 7;
    const float q = bf2f(qkv[h * 64 + lane]);
    float m = -1e30f, s = 0.f, o = 0.f;
    const int j0 = p * 32;
    for (int jj = 0; jj < 32; ++jj) {
      const int j = j0 + jj;
      float kv = bf2f(qkv[(size_t)j * 3072 + 1024 + h * 64 + lane]);
      float pr = q * kv;
#pragma unroll
      for (int off = 32; off; off >>= 1) pr += __shfl_xor(pr, off);
      pr *= 0.125f;
      float mn = fmaxf(m, pr);
      float c = __expf(m - mn);
      float e = __expf(pr - mn);
      float v = bf2f(qkv[(size_t)j * 3072 + 2048 + h * 64 + lane]);
      s = s * c + e;
      o = o * c + e * v;
      m = mn;
    }
    float* dst = prt + ((size_t)h * 128 + p) * 72;
    if (lane == 0) { dst[0] = m; dst[1] = s; }
    dst[2 + lane] = o;
    return;
  }

  const int i = blockIdx.x * 4 + wid + 1;
  if (i >= SL) return;
  const unsigned short* rowQ = qkv + (size_t)i * 3072 + lane * 16;

  float q[16];
  {
    uint4 a = *(const uint4*)rowQ;
    uint4 b = *(const uint4*)(rowQ + 8);
    unsigned int uu[8] = {a.x, a.y, a.z, a.w, b.x, b.y, b.z, b.w};
#pragma unroll
    for (int c = 0; c < 8; ++c) { q[2 * c] = bflo(uu[c]); q[2 * c + 1] = bfhi(uu[c]); }
  }

  float sc[9];
#pragma unroll
  for (int t = 0; t < 9; ++t) {
    int j = (t == 0) ? 0 : (i - 8 + t);
    bool valid = (t == 0) || (j >= 1);
    int jc = valid ? j : 0;
    const unsigned short* pk = qkv + (size_t)jc * 3072 + 1024 + lane * 16;
    uint4 a = *(const uint4*)pk;
    uint4 b = *(const uint4*)(pk + 8);
    unsigned int uu[8] = {a.x, a.y, a.z, a.w, b.x, b.y, b.z, b.w};
    float pr = 0.f;
#pragma unroll
    for (int c = 0; c < 8; ++c) pr += bflo(uu[c]) * q[2 * c] + bfhi(uu[c]) * q[2 * c + 1];
    pr += __shfl_xor(pr, 1);
    pr += __shfl_xor(pr, 2);
    sc[t] = valid ? pr * 0.125f : -1e30f;
  }

  float mx = sc[0];
#pragma unroll
  for (int t = 1; t < 9; ++t) mx = fmaxf(mx, sc[t]);
  float s = 0.f;
#pragma unroll
  for (int t = 0; t < 9; ++t) { float e = __expf(sc[t] - mx); sc[t] = e; s += e; }
  const float inv = 1.0f / s;

  float o[16] = {};
#pragma unroll
  for (int t = 0; t < 9; ++t) {
    int j = (t == 0) ? 0 : (i - 8 + t);
    bool valid = (t == 0) || (j >= 1);
    int jc = valid ? j : 0;
    const unsigned short* pv = qkv + (size_t)jc * 3072 + 2048 + lane * 16;
    uint4 a = *(const uint4*)pv;
    uint4 b = *(const uint4*)(pv + 8);
    unsigned int uu[8] = {a.x, a.y, a.z, a.w, b.x, b.y, b.z, b.w};
#pragma unroll
    for (int c = 0; c < 8; ++c) {
      o[2 * c]     += sc[t] * bflo(uu[c]);
      o[2 * c + 1] += sc[t] * bfhi(uu[c]);
    }
  }

  unsigned int wv[8];
#pragma unroll
  for (int c = 0; c < 8; ++c)
    wv[c] = (unsigned int)f2bf(o[2 * c] * inv) | ((unsigned int)f2bf(o[2 * c + 1] * inv) << 16);
  unsigned short* po = atb + (size_t)i * 1024 + lane * 16;
  uint4 s0; s0.x = wv[0]; s0.y = wv[1]; s0.z = wv[2]; s0.w = wv[3];
  uint4 s1; s1.x = wv[4]; s1.y = wv[5]; s1.z = wv[6]; s1.w = wv[7];
  *(uint4*)po = s0;
  *(uint4*)(po + 8) = s1;
}

// ---------------- row-0 combine: 16 blocks, wave-parallel over partials ----
__global__ __launch_bounds__(64)
void attn_row0_combine(const float* __restrict__ prt, unsigned short* __restrict__ atb) {
  const int h = blockIdx.x;
  const int lane = threadIdx.x;
  const float* base = prt + (size_t)h * 128 * 72;
  __shared__ float cbuf[128];
  float m0 = base[lane * 72];
  float m1 = base[(lane + 64) * 72];
  float M = fmaxf(m0, m1);
#pragma unroll
  for (int off = 32; off; off >>= 1) M = fmaxf(M, __shfl_xor(M, off));
  float c0 = __expf(m0 - M), c1 = __expf(m1 - M);
  float ls = base[lane * 72 + 1] * c0 + base[(lane + 64) * 72 + 1] * c1;
#pragma unroll
  for (int off = 32; off; off >>= 1) ls += __shfl_xor(ls, off);
  cbuf[lane] = c0;
  cbuf[lane + 64] = c1;
  __syncthreads();
  float o = 0.f;
#pragma unroll 8
  for (int p = 0; p < 128; ++p) o += cbuf[p] * base[p * 72 + 2 + lane];
  atb[h * 64 + lane] = f2bf(o / ls);
}

extern "C" void kernel_launch(void* const* d_in, const int* in_sizes, int n_in,
                              void* d_out, int out_size, void* d_ws, size_t ws_size,
                              hipStream_t stream) {
  const float* x  = (const float*)d_in[0];
  const float* Wq = (const float*)d_in[1];
  const float* Wk = (const float*)d_in[2];
  const float* Wv = (const float*)d_in[3];
  const float* Wo = (const float*)d_in[4];
  const float* fc = (const float*)d_in[5];
  const float* fs = (const float*)d_in[6];
  float* out = (float*)d_out;

  char* ws = (char*)d_ws;
  unsigned short* xb   = (unsigned short*)(ws);                      // 8 MB  bf16 x
  unsigned short* w3b  = (unsigned short*)(ws + ((size_t)8 << 20));  // 6 MB  bf16 [Wq;Wk;Wv]
  unsigned short* wob  = (unsigned short*)(ws + ((size_t)14 << 20)); // 2 MB  bf16 Wo
  unsigned short* qkvb = (unsigned short*)(ws + ((size_t)16 << 20)); // 24 MB bf16 QKV (roped)
  unsigned short* atb  = (unsigned short*)(ws + ((size_t)40 << 20)); // 8 MB  bf16 attn out
  float*          prt  = (float*)(ws + ((size_t)48 << 20));          // 0.6 MB row0 partials

  cast_all<<<(2 * (1 << 20)) / 256, 256, 0, stream>>>(x, Wq, Wk, Wv, Wo, xb, w3b, wob);

  // GEMM1: 128x192 tile BK=64 4-phase depth-2, grid 16x32 = 512 blocks (2/CU)
  dim3 g1(3072 / 192, SL / 128);
  gemm1_rope<<<g1, 512, 0, stream>>>(xb, w3b, qkvb, fc, fs);

  attn_fused<<<1536, 256, 0, stream>>>(qkvb, atb, prt);
  attn_row0_combine<<<NH, 64, 0, stream>>>(prt, atb);

  // GEMM2: 128x128 tile BK=128 4-phase depth-2, 8 waves, no XCD swizzle
  dim3 g2(DM / 128, SL / 128);
  gemm2_bk128<<<g2, 512, 0, stream>>>(atb, wob, out);
}

// Round 22
// 85.053 us; speedup vs baseline: 1.0700x; 1.0280x over previous
//
#include <hip/hip_runtime.h>
#include <stdint.h>

#define SL 4096
#define DM 1024
#define NH 16
#define HDIM 64

typedef short short8 __attribute__((ext_vector_type(8)));
typedef float f32x4 __attribute__((ext_vector_type(4)));

__device__ __forceinline__ unsigned short f2bf(float f) {
  unsigned int u = __float_as_uint(f);
  u += 0x7FFF + ((u >> 16) & 1);
  return (unsigned short)(u >> 16);
}
__device__ __forceinline__ float bf2f(unsigned short u) {
  return __uint_as_float((unsigned int)u << 16);
}
__device__ __forceinline__ float bflo(unsigned int u) { return __uint_as_float(u << 16); }
__device__ __forceinline__ float bfhi(unsigned int u) { return __uint_as_float(u & 0xffff0000u); }

__device__ __forceinline__ void gload_lds16(const void* g, void* l) {
  __builtin_amdgcn_global_load_lds((const __attribute__((address_space(1))) void*)g,
                                   (__attribute__((address_space(3))) void*)l, 16, 0, 0);
}
#define SBAR()                                  \
  do {                                          \
    __builtin_amdgcn_sched_barrier(0);          \
    __builtin_amdgcn_s_barrier();               \
    __builtin_amdgcn_sched_barrier(0);          \
  } while (0)
#define LGKM0() asm volatile("s_waitcnt lgkmcnt(0)" ::: "memory")

// ---------------- fused cast: x + 4 weight mats ----------------
__global__ void cast_all(const float* __restrict__ x,
                         const float* __restrict__ Wq, const float* __restrict__ Wk,
                         const float* __restrict__ Wv, const float* __restrict__ Wo,
                         unsigned short* __restrict__ xb,
                         unsigned short* __restrict__ w3b, unsigned short* __restrict__ wob) {
  int i = blockIdx.x * blockDim.x + threadIdx.x;  // 0 .. 2*2^20-1
  const float* src;
  unsigned short* dst;
  int off;
  if (i < (1 << 20)) {
    src = x; dst = xb; off = i;
  } else {
    int wsel = i - (1 << 20);
    int seg = wsel >> 18;                         // 0..3
    off = wsel & 262143;
    src = (seg == 0) ? Wq : (seg == 1) ? Wk : (seg == 2) ? Wv : Wo;
    dst = (seg < 3) ? (w3b + (size_t)seg * DM * DM) : wob;
  }
  float4 v = ((const float4*)src)[off];
  ushort4 o = make_ushort4(f2bf(v.x), f2bf(v.y), f2bf(v.z), f2bf(v.w));
  ((ushort4*)dst)[off] = o;
}

// ============ GEMM1: 128x192 tile, BK=64, 8 waves, 4-phase, DEPTH-2 =========
// (r16-proven, 2 blocks/CU — best measured GEMM1 config.) Reads ph1-2 only,
// LGKM0 in ph2, same-buffer t+2 staging ph3-4, ph4 vmcnt(5).
__global__ __launch_bounds__(512, 4)
void gemm1_rope(const unsigned short* __restrict__ A,
                const unsigned short* __restrict__ B,
                unsigned short* __restrict__ C,
                const float* __restrict__ fc, const float* __restrict__ fs) {
  constexpr int K = 1024, LDA = 1024, LDC = 3072, NT = K / 64;
  __shared__ __align__(16) unsigned short As[2][128 * 64];
  __shared__ __align__(16) unsigned short Bs[2][192 * 64];
  const int tid = threadIdx.x, w = tid >> 6, lane = tid & 63;
  const int wr = w >> 2, wc = w & 3;  // 2 x 4 wave grid, wave-tile 64x48

  const int gx = gridDim.x;           // 16 (N tiles of 192)
  const int total = gx * gridDim.y;   // 512
  const int lin = blockIdx.y * gx + blockIdx.x;
  const int swz = (lin & 7) * (total >> 3) + (lin >> 3);
  const int brow = (swz / gx) * 128;
  const int bcol = (swz % gx) * 192;

  const unsigned short* gA[2];
  const unsigned short* gB[3];
#pragma unroll
  for (int l = 0; l < 2; ++l) {
    int idx = l * 512 + tid;            // rows [0,128)
    int row_l = idx >> 3, c = idx & 7;
    int csrc = c ^ ((row_l >> 1) & 7);
    gA[l] = A + (size_t)(brow + row_l) * LDA + csrc * 8;
  }
#pragma unroll
  for (int l = 0; l < 3; ++l) {
    int idx = l * 512 + tid;            // rows [0,192)
    int row_l = idx >> 3, c = idx & 7;
    int csrc = c ^ ((row_l >> 1) & 7);
    gB[l] = B + (size_t)(bcol + row_l) * LDA + csrc * 8;
  }

  auto STG_A = [&](int t) {             // 2 loads, rows [0,128)
    const int buf = t & 1;
#pragma unroll
    for (int l = 0; l < 2; ++l)
      gload_lds16(gA[l] + t * 64, &As[buf][(l * 512 + w * 64) * 8]);
  };
  auto STG_B_a = [&](int t) {           // 2 loads, rows [0,128)
    const int buf = t & 1;
#pragma unroll
    for (int l = 0; l < 2; ++l)
      gload_lds16(gB[l] + t * 64, &Bs[buf][(l * 512 + w * 64) * 8]);
  };
  auto STG_B_b = [&](int t) {           // 1 load, rows [128,192)
    const int buf = t & 1;
    gload_lds16(gB[2] + t * 64, &Bs[buf][(2 * 512 + w * 64) * 8]);
  };

  const int lrow = lane & 15, h4 = lane >> 4;
  const int g3 = (lane >> 1) & 7;
  const int u2 = h4 ^ (g3 & 3);
  const int gv = g3 >> 2;
  const int co0 = ((((0 ^ gv) << 2) | u2)) * 8;
  const int co1 = ((((1 ^ gv) << 2) | u2)) * 8;

  f32x4 acc[4][3] = {};
  short8 a0[4], a1[4], b0[3], b1[3];

  // prologue: tiles 0 and 1 fully staged (5 loads each); wait tile 0
  STG_A(0); STG_B_a(0); STG_B_b(0);
  STG_A(1); STG_B_a(1); STG_B_b(1);
  asm volatile("s_waitcnt vmcnt(5)" ::: "memory");
  SBAR();

  for (int t = 0; t < NT; ++t) {
    const int buf = t & 1;
    const unsigned short* Ab = &As[buf][(wr * 64 + lrow) * 64];
    const unsigned short* Bb = &Bs[buf][(wc * 48 + lrow) * 64];
    // ---- phase 1: read k0 frags; MFMA ks0 (all 12)
#pragma unroll
    for (int n = 0; n < 3; ++n) b0[n] = *(const short8*)&Bb[n * 16 * 64 + co0];
#pragma unroll
    for (int m = 0; m < 4; ++m) a0[m] = *(const short8*)&Ab[m * 16 * 64 + co0];
    SBAR();
    __builtin_amdgcn_s_setprio(1);
#pragma unroll
    for (int m = 0; m < 4; ++m)
#pragma unroll
      for (int n = 0; n < 3; ++n)
        acc[m][n] = __builtin_amdgcn_mfma_f32_16x16x32_bf16(a0[m], b0[n], acc[m][n], 0, 0, 0);
    __builtin_amdgcn_s_setprio(0);
    // ---- phase 2: read k1 frags; LGKM0; MFMA ks1 n0
#pragma unroll
    for (int n = 0; n < 3; ++n) b1[n] = *(const short8*)&Bb[n * 16 * 64 + co1];
#pragma unroll
    for (int m = 0; m < 4; ++m) a1[m] = *(const short8*)&Ab[m * 16 * 64 + co1];
    LGKM0();   // all reads of this buffer retired before ph3 staging
    SBAR();
    __builtin_amdgcn_s_setprio(1);
#pragma unroll
    for (int m = 0; m < 4; ++m)
      acc[m][0] = __builtin_amdgcn_mfma_f32_16x16x32_bf16(a1[m], b1[0], acc[m][0], 0, 0, 0);
    __builtin_amdgcn_s_setprio(0);
    // ---- phase 3: stage A(t+2); MFMA ks1 n1
    if (t + 2 < NT) STG_A(t + 2);
    SBAR();
    __builtin_amdgcn_s_setprio(1);
#pragma unroll
    for (int m = 0; m < 4; ++m)
      acc[m][1] = __builtin_amdgcn_mfma_f32_16x16x32_bf16(a1[m], b1[1], acc[m][1], 0, 0, 0);
    __builtin_amdgcn_s_setprio(0);
    // ---- phase 4: stage B(t+2); counted vmcnt; MFMA ks1 n2
    if (t + 2 < NT) { STG_B_a(t + 2); STG_B_b(t + 2); }
    if (t >= NT - 2) {
      asm volatile("s_waitcnt vmcnt(0)" ::: "memory");
    } else {
      asm volatile("s_waitcnt vmcnt(5)" ::: "memory");
    }
    SBAR();
    __builtin_amdgcn_s_setprio(1);
#pragma unroll
    for (int m = 0; m < 4; ++m)
      acc[m][2] = __builtin_amdgcn_mfma_f32_16x16x32_bf16(a1[m], b1[2], acc[m][2], 0, 0, 0);
    __builtin_amdgcn_s_setprio(0);
  }

  // ---- epilogue: RoPE (abs cols<2048, per-frag) + bf16 store
  const int er = (lane >> 4) * 4;
  const int ec = lane & 15;
#pragma unroll
  for (int n = 0; n < 3; ++n) {
    if (bcol + wc * 48 + n * 16 < 2048) {
      const int p = ((wc * 48 + n * 16 + ec) & 63) >> 1;
#pragma unroll
      for (int m = 0; m < 4; ++m) {
#pragma unroll
        for (int r = 0; r < 4; ++r) {
          const int row = brow + wr * 64 + m * 16 + er + r;
          float v = acc[m][n][r];
          float pv = __shfl_xor(v, 1);
          float cs = fc[row * 32 + p], sn = fs[row * 32 + p];
          acc[m][n][r] = (lane & 1) ? (pv * sn + v * cs) : (v * cs - pv * sn);
        }
      }
    }
  }
#pragma unroll
  for (int m = 0; m < 4; ++m)
#pragma unroll
    for (int n = 0; n < 3; ++n) {
      unsigned short* cp = C + (size_t)(brow + wr * 64 + m * 16 + er) * LDC +
                           (bcol + wc * 48 + n * 16 + ec);
#pragma unroll
      for (int r = 0; r < 4; ++r) cp[(size_t)r * LDC] = f2bf(acc[m][n][r]);
    }
}

// ============ GEMM2: 128x128 tile, BK=128 (two 64-wide halves), 8 waves =====
// (r18-proven, WITH XCD swizzle — measured best.) Non-temporal C store:
// output is final, never re-read on device -> keep L2 for A/B panels.
__global__ __launch_bounds__(512)
void gemm2_bk128(const unsigned short* __restrict__ A,
                 const unsigned short* __restrict__ B,
                 float* __restrict__ C) {
  constexpr int K = 1024, LDA = 1024, LDC = 1024, NT = K / 128;  // 8
  __shared__ __align__(16) unsigned short As2[2][2][128 * 64];   // [buf][half]
  __shared__ __align__(16) unsigned short Bs2[2][2][128 * 64];
  const int tid = threadIdx.x, w = tid >> 6, lane = tid & 63;
  const int wr = w >> 2, wc = w & 3;   // 2 x 4 wave grid, wave-tile 64x32

  const int gx = gridDim.x;            // 8
  const int total = gx * gridDim.y;    // 256
  const int lin = blockIdx.y * gx + blockIdx.x;
  const int swz = (lin & 7) * (total >> 3) + (lin >> 3);
  const int brow = (swz / gx) * 128;
  const int bcol = (swz % gx) * 128;

  const unsigned short* gA[2];
  const unsigned short* gB[2];
#pragma unroll
  for (int l = 0; l < 2; ++l) {
    int idx = l * 512 + tid;
    int row_l = idx >> 3, c = idx & 7;
    int csrc = c ^ ((row_l >> 1) & 7);
    gA[l] = A + (size_t)(brow + row_l) * LDA + csrc * 8;
    gB[l] = B + (size_t)(bcol + row_l) * LDA + csrc * 8;
  }

  auto STG_A = [&](int t, int h) {
    const int buf = t & 1;
#pragma unroll
    for (int l = 0; l < 2; ++l)
      gload_lds16(gA[l] + t * 128 + h * 64, &As2[buf][h][(l * 512 + w * 64) * 8]);
  };
  auto STG_B = [&](int t, int h) {
    const int buf = t & 1;
#pragma unroll
    for (int l = 0; l < 2; ++l)
      gload_lds16(gB[l] + t * 128 + h * 64, &Bs2[buf][h][(l * 512 + w * 64) * 8]);
  };

  const int lrow = lane & 15, h4 = lane >> 4;
  const int g3 = (lane >> 1) & 7;
  const int u2 = h4 ^ (g3 & 3);
  const int gv = g3 >> 2;
  const int co0 = ((((0 ^ gv) << 2) | u2)) * 8;
  const int co1 = ((((1 ^ gv) << 2) | u2)) * 8;

  f32x4 acc[4][2] = {};
  short8 a0[4], a1[4], a2[4], a3[4], b0[2], b1[2], b2[2], b3[2];

  STG_A(0, 0); STG_A(0, 1); STG_B(0, 0); STG_B(0, 1);
  STG_A(1, 0); STG_A(1, 1); STG_B(1, 0); STG_B(1, 1);
  asm volatile("s_waitcnt vmcnt(8)" ::: "memory");
  SBAR();

  for (int t = 0; t < NT; ++t) {
    const int buf = t & 1;
    const unsigned short* Ab0 = &As2[buf][0][(wr * 64 + lrow) * 64];
    const unsigned short* Ab1 = &As2[buf][1][(wr * 64 + lrow) * 64];
    const unsigned short* Bb0 = &Bs2[buf][0][(wc * 32 + lrow) * 64];
    const unsigned short* Bb1 = &Bs2[buf][1][(wc * 32 + lrow) * 64];
    // ---- phase 1: read half0 frags (12); MFMA slice0
#pragma unroll
    for (int n = 0; n < 2; ++n) { b0[n] = *(const short8*)&Bb0[n * 16 * 64 + co0];
                                  b1[n] = *(const short8*)&Bb0[n * 16 * 64 + co1]; }
#pragma unroll
    for (int m = 0; m < 4; ++m) { a0[m] = *(const short8*)&Ab0[m * 16 * 64 + co0];
                                  a1[m] = *(const short8*)&Ab0[m * 16 * 64 + co1]; }
    SBAR();
    __builtin_amdgcn_s_setprio(1);
#pragma unroll
    for (int m = 0; m < 4; ++m)
#pragma unroll
      for (int n = 0; n < 2; ++n)
        acc[m][n] = __builtin_amdgcn_mfma_f32_16x16x32_bf16(a0[m], b0[n], acc[m][n], 0, 0, 0);
    __builtin_amdgcn_s_setprio(0);
    // ---- phase 2: read half1 frags (12); LGKM0; MFMA slice1
#pragma unroll
    for (int n = 0; n < 2; ++n) { b2[n] = *(const short8*)&Bb1[n * 16 * 64 + co0];
                                  b3[n] = *(const short8*)&Bb1[n * 16 * 64 + co1]; }
#pragma unroll
    for (int m = 0; m < 4; ++m) { a2[m] = *(const short8*)&Ab1[m * 16 * 64 + co0];
                                  a3[m] = *(const short8*)&Ab1[m * 16 * 64 + co1]; }
    LGKM0();   // all reads of this buffer retired before ph3 staging
    SBAR();
    __builtin_amdgcn_s_setprio(1);
#pragma unroll
    for (int m = 0; m < 4; ++m)
#pragma unroll
      for (int n = 0; n < 2; ++n)
        acc[m][n] = __builtin_amdgcn_mfma_f32_16x16x32_bf16(a1[m], b1[n], acc[m][n], 0, 0, 0);
    __builtin_amdgcn_s_setprio(0);
    // ---- phase 3: stage A(t+2,h0)+B(t+2,h0); MFMA slice2
    if (t + 2 < NT) { STG_A(t + 2, 0); STG_B(t + 2, 0); }
    SBAR();
    __builtin_amdgcn_s_setprio(1);
#pragma unroll
    for (int m = 0; m < 4; ++m)
#pragma unroll
      for (int n = 0; n < 2; ++n)
        acc[m][n] = __builtin_amdgcn_mfma_f32_16x16x32_bf16(a2[m], b2[n], acc[m][n], 0, 0, 0);
    __builtin_amdgcn_s_setprio(0);
    // ---- phase 4: stage A(t+2,h1)+B(t+2,h1); counted vmcnt; MFMA slice3
    if (t + 2 < NT) { STG_A(t + 2, 1); STG_B(t + 2, 1); }
    if (t >= NT - 2) {
      asm volatile("s_waitcnt vmcnt(0)" ::: "memory");
    } else {
      asm volatile("s_waitcnt vmcnt(8)" ::: "memory");
    }
    SBAR();
    __builtin_amdgcn_s_setprio(1);
#pragma unroll
    for (int m = 0; m < 4; ++m)
#pragma unroll
      for (int n = 0; n < 2; ++n)
        acc[m][n] = __builtin_amdgcn_mfma_f32_16x16x32_bf16(a3[m], b3[n], acc[m][n], 0, 0, 0);
    __builtin_amdgcn_s_setprio(0);
  }

  const int er = (lane >> 4) * 4;
  const int ec = lane & 15;
#pragma unroll
  for (int m = 0; m < 4; ++m)
#pragma unroll
    for (int n = 0; n < 2; ++n) {
      float* cp = C + (size_t)(brow + wr * 64 + m * 16 + er) * LDC +
                  (bcol + wc * 32 + n * 16 + ec);
#pragma unroll
      for (int r = 0; r < 4; ++r)
        __builtin_nontemporal_store(acc[m][n][r], cp + (size_t)r * LDC);
    }
}

// ---------------- fused attention: rows 1..L-1 + row-0 flash partials ------
__global__ __launch_bounds__(256)
void attn_fused(const unsigned short* __restrict__ qkv, unsigned short* __restrict__ atb,
                float* __restrict__ prt) {
  const int wid = threadIdx.x >> 6;
  const int lane = threadIdx.x & 63;
  if (blockIdx.x >= 1024) {
    const int u = (blockIdx.x - 1024) * 4 + wid;
    const int p = u & 127, h = u >> 7;
    const float q = bf2f(qkv[h * 64 + lane]);
    float m = -1e30f, s = 0.f, o = 0.f;
    const int j0 = p * 32;
    for (int jj = 0; jj < 32; ++jj) {
      const int j = j0 + jj;
      float kv = bf2f(qkv[(size_t)j * 3072 + 1024 + h * 64 + lane]);
      float pr = q * kv;
#pragma unroll
      for (int off = 32; off; off >>= 1) pr += __shfl_xor(pr, off);
      pr *= 0.125f;
      float mn = fmaxf(m, pr);
      float c = __expf(m - mn);
      float e = __expf(pr - mn);
      float v = bf2f(qkv[(size_t)j * 3072 + 2048 + h * 64 + lane]);
      s = s * c + e;
      o = o * c + e * v;
      m = mn;
    }
    float* dst = prt + ((size_t)h * 128 + p) * 72;
    if (lane == 0) { dst[0] = m; dst[1] = s; }
    dst[2 + lane] = o;
    return;
  }

  const int i = blockIdx.x * 4 + wid + 1;
  if (i >= SL) return;
  const unsigned short* rowQ = qkv + (size_t)i * 3072 + lane * 16;

  float q[16];
  {
    uint4 a = *(const uint4*)rowQ;
    uint4 b = *(const uint4*)(rowQ + 8);
    unsigned int uu[8] = {a.x, a.y, a.z, a.w, b.x, b.y, b.z, b.w};
#pragma unroll
    for (int c = 0; c < 8; ++c) { q[2 * c] = bflo(uu[c]); q[2 * c + 1] = bfhi(uu[c]); }
  }

  float sc[9];
#pragma unroll
  for (int t = 0; t < 9; ++t) {
    int j = (t == 0) ? 0 : (i - 8 + t);
    bool valid = (t == 0) || (j >= 1);
    int jc = valid ? j : 0;
    const unsigned short* pk = qkv + (size_t)jc * 3072 + 1024 + lane * 16;
    uint4 a = *(const uint4*)pk;
    uint4 b = *(const uint4*)(pk + 8);
    unsigned int uu[8] = {a.x, a.y, a.z, a.w, b.x, b.y, b.z, b.w};
    float pr = 0.f;
#pragma unroll
    for (int c = 0; c < 8; ++c) pr += bflo(uu[c]) * q[2 * c] + bfhi(uu[c]) * q[2 * c + 1];
    pr += __shfl_xor(pr, 1);
    pr += __shfl_xor(pr, 2);
    sc[t] = valid ? pr * 0.125f : -1e30f;
  }

  float mx = sc[0];
#pragma unroll
  for (int t = 1; t < 9; ++t) mx = fmaxf(mx, sc[t]);
  float s = 0.f;
#pragma unroll
  for (int t = 0; t < 9; ++t) { float e = __expf(sc[t] - mx); sc[t] = e; s += e; }
  const float inv = 1.0f / s;

  float o[16] = {};
#pragma unroll
  for (int t = 0; t < 9; ++t) {
    int j = (t == 0) ? 0 : (i - 8 + t);
    bool valid = (t == 0) || (j >= 1);
    int jc = valid ? j : 0;
    const unsigned short* pv = qkv + (size_t)jc * 3072 + 2048 + lane * 16;
    uint4 a = *(const uint4*)pv;
    uint4 b = *(const uint4*)(pv + 8);
    unsigned int uu[8] = {a.x, a.y, a.z, a.w, b.x, b.y, b.z, b.w};
#pragma unroll
    for (int c = 0; c < 8; ++c) {
      o[2 * c]     += sc[t] * bflo(uu[c]);
      o[2 * c + 1] += sc[t] * bfhi(uu[c]);
    }
  }

  unsigned int wv[8];
#pragma unroll
  for (int c = 0; c < 8; ++c)
    wv[c] = (unsigned int)f2bf(o[2 * c] * inv) | ((unsigned int)f2bf(o[2 * c + 1] * inv) << 16);
  unsigned short* po = atb + (size_t)i * 1024 + lane * 16;
  uint4 s0; s0.x = wv[0]; s0.y = wv[1]; s0.z = wv[2]; s0.w = wv[3];
  uint4 s1; s1.x = wv[4]; s1.y = wv[5]; s1.z = wv[6]; s1.w = wv[7];
  *(uint4*)po = s0;
  *(uint4*)(po + 8) = s1;
}

// ---------------- row-0 combine: 16 blocks, wave-parallel over partials ----
__global__ __launch_bounds__(64)
void attn_row0_combine(const float* __restrict__ prt, unsigned short* __restrict__ atb) {
  const int h = blockIdx.x;
  const int lane = threadIdx.x;
  const float* base = prt + (size_t)h * 128 * 72;
  __shared__ float cbuf[128];
  float m0 = base[lane * 72];
  float m1 = base[(lane + 64) * 72];
  float M = fmaxf(m0, m1);
#pragma unroll
  for (int off = 32; off; off >>= 1) M = fmaxf(M, __shfl_xor(M, off));
  float c0 = __expf(m0 - M), c1 = __expf(m1 - M);
  float ls = base[lane * 72 + 1] * c0 + base[(lane + 64) * 72 + 1] * c1;
#pragma unroll
  for (int off = 32; off; off >>= 1) ls += __shfl_xor(ls, off);
  cbuf[lane] = c0;
  cbuf[lane + 64] = c1;
  __syncthreads();
  float o = 0.f;
#pragma unroll 8
  for (int p = 0; p < 128; ++p) o += cbuf[p] * base[p * 72 + 2 + lane];
  atb[h * 64 + lane] = f2bf(o / ls);
}

extern "C" void kernel_launch(void* const* d_in, const int* in_sizes, int n_in,
                              void* d_out, int out_size, void* d_ws, size_t ws_size,
                              hipStream_t stream) {
  const float* x  = (const float*)d_in[0];
  const float* Wq = (const float*)d_in[1];
  const float* Wk = (const float*)d_in[2];
  const float* Wv = (const float*)d_in[3];
  const float* Wo = (const float*)d_in[4];
  const float* fc = (const float*)d_in[5];
  const float* fs = (const float*)d_in[6];
  float* out = (float*)d_out;

  char* ws = (char*)d_ws;
  unsigned short* xb   = (unsigned short*)(ws);                      // 8 MB  bf16 x
  unsigned short* w3b  = (unsigned short*)(ws + ((size_t)8 << 20));  // 6 MB  bf16 [Wq;Wk;Wv]
  unsigned short* wob  = (unsigned short*)(ws + ((size_t)14 << 20)); // 2 MB  bf16 Wo
  unsigned short* qkvb = (unsigned short*)(ws + ((size_t)16 << 20)); // 24 MB bf16 QKV (roped)
  unsigned short* atb  = (unsigned short*)(ws + ((size_t)40 << 20)); // 8 MB  bf16 attn out
  float*          prt  = (float*)(ws + ((size_t)48 << 20));          // 0.6 MB row0 partials

  cast_all<<<(2 * (1 << 20)) / 256, 256, 0, stream>>>(x, Wq, Wk, Wv, Wo, xb, w3b, wob);

  // GEMM1: 128x192 tile BK=64 4-phase depth-2, grid 16x32 = 512 blocks (2/CU)
  dim3 g1(3072 / 192, SL / 128);
  gemm1_rope<<<g1, 512, 0, stream>>>(xb, w3b, qkvb, fc, fs);

  attn_fused<<<1536, 256, 0, stream>>>(qkvb, atb, prt);
  attn_row0_combine<<<NH, 64, 0, stream>>>(prt, atb);

  // GEMM2: 128x128 tile BK=128 4-phase depth-2, 8 waves, XCD swizzle (r18)
  dim3 g2(DM / 128, SL / 128);
  gemm2_bk128<<<g2, 512, 0, stream>>>(atb, wob, out);
}